// Round 4
// baseline (599.850 us; speedup 1.0000x reference)
//
#include <hip/hip_runtime.h>
#include <math.h>

typedef float f2 __attribute__((ext_vector_type(2)));

namespace {
constexpr int TOUT = 32;            // output tile side
constexpr int HALO = 15;            // 16-tap VALID conv halo
constexpr int TIN  = TOUT + HALO;   // 47 rows of horizontal-conv output
constexpr int HLD  = 36;            // hb row stride (floats), 144 B = 16B-aligned
constexpr int IMG  = 512;
constexpr int OUTW = IMG - HALO;    // 497
constexpr int NBLK = 16 * 16 * 96;  // 24576 blocks

struct GaussWin { float g[16]; };

__device__ __forceinline__ f2 fma2(f2 a, f2 b, f2 c) {
    return __builtin_elementwise_fma(a, b, c);
}
}

// One block = one 32x32 output tile of one (batch,channel) plane.
// Packed-f32 (v_pk_fma_f32) version: phase AB packs ROW PAIRS (2 rows share
// weights, independent inputs -> aligned packed ops), phase C packs COLUMN
// PAIRS (b64 LDS reads at ~2x the b32 byte rate).
// Phase AB: 192 threads = 24 row-pairs x 8 col-segments of 4 outputs. Load
//   19 floats x 2 rows x 2 images into f2 regs, fuse MSE, 16-tap horizontal
//   conv for 4 signals (a, b, a^2+b^2, a*b), scalar-store into hb[4][47][36].
// Phase C: 128 threads = 16 col-pairs x 8 row-groups of 4. 19 b64 reads per
//   signal serve 4x2 outputs; packed vertical conv; SSIM map with v_rcp.
// Tail: per-block double2 partial (R2 showed same-address f64 atomics
//   serialize at ~13 ns = 2.2x whole-kernel cost); reduce_kernel sums.
template <bool TWO_STAGE>
__global__ __launch_bounds__(256, 4) void ssim_mse_kernel(
    const float* __restrict__ img1,
    const float* __restrict__ img2,
    GaussWin win,
    double2* __restrict__ partial,
    double*  __restrict__ accum)
{
    __shared__ float hb[4][TIN][HLD];   // 27,072 B -> 6 blocks/CU by LDS
    __shared__ float red[2][4];

    const int tid = threadIdx.x;
    const int ox0 = blockIdx.x * TOUT;
    const int oy0 = blockIdx.y * TOUT;
    const size_t plane_off = (size_t)blockIdx.z * (IMG * IMG);
    const float* __restrict__ p1 = img1 + plane_off;
    const float* __restrict__ p2 = img2 + plane_off;

    float mse_local = 0.0f;

    // ---------------- Phase AB: load + MSE + horizontal conv ----------------
    if (tid < 192) {
        const int pr  = tid >> 3;       // row pair 0..23 -> rows 2pr, 2pr+1
        const int seg = tid & 7;        // col segment: 4 outputs each
        const int r0  = 2 * pr;
        const int r1  = r0 + 1;
        const int gy0 = oy0 + r0;
        const int gy1 = oy0 + r1;
        const int c0  = ox0 + 4 * seg;

        f2 PA[19], PB[19];              // (row0, row1) packed
        const bool fast = (gy1 < IMG) & (c0 + 19 <= IMG);
        if (fast) {
            const float* __restrict__ pa0 = p1 + (size_t)gy0 * IMG + c0;
            const float* __restrict__ pa1 = pa0 + IMG;
            const float* __restrict__ pb0 = p2 + (size_t)gy0 * IMG + c0;
            const float* __restrict__ pb1 = pb0 + IMG;
            #pragma unroll
            for (int q = 0; q < 4; ++q) {
                const float4 a0 = *(const float4*)(pa0 + 4 * q);
                const float4 a1 = *(const float4*)(pa1 + 4 * q);
                const float4 b0 = *(const float4*)(pb0 + 4 * q);
                const float4 b1 = *(const float4*)(pb1 + 4 * q);
                PA[4*q+0] = f2{a0.x, a1.x}; PA[4*q+1] = f2{a0.y, a1.y};
                PA[4*q+2] = f2{a0.z, a1.z}; PA[4*q+3] = f2{a0.w, a1.w};
                PB[4*q+0] = f2{b0.x, b1.x}; PB[4*q+1] = f2{b0.y, b1.y};
                PB[4*q+2] = f2{b0.z, b1.z}; PB[4*q+3] = f2{b0.w, b1.w};
            }
            const float2 ta0 = *(const float2*)(pa0 + 16);
            const float2 ta1 = *(const float2*)(pa1 + 16);
            const float2 tb0 = *(const float2*)(pb0 + 16);
            const float2 tb1 = *(const float2*)(pb1 + 16);
            PA[16] = f2{ta0.x, ta1.x}; PA[17] = f2{ta0.y, ta1.y};
            PB[16] = f2{tb0.x, tb1.x}; PB[17] = f2{tb0.y, tb1.y};
            PA[18] = f2{pa0[18], pa1[18]};
            PB[18] = f2{pb0[18], pb1[18]};
        } else {
            const int g0 = gy0 < IMG ? gy0 : (IMG - 1);
            const int g1 = gy1 < IMG ? gy1 : (IMG - 1);
            const float* __restrict__ pa0 = p1 + (size_t)g0 * IMG;
            const float* __restrict__ pa1 = p1 + (size_t)g1 * IMG;
            const float* __restrict__ pb0 = p2 + (size_t)g0 * IMG;
            const float* __restrict__ pb1 = p2 + (size_t)g1 * IMG;
            #pragma unroll
            for (int k = 0; k < 19; ++k) {
                const int gx = (c0 + k) < IMG ? (c0 + k) : (IMG - 1);
                PA[k] = f2{pa0[gx], pa1[gx]};
                PB[k] = f2{pb0[gx], pb1[gx]};
            }
        }

        // MSE over owned pixels: row pairs 0..15 (= rows 0..31), 4 owned cols
        if (pr < 16) {
            f2 acc = f2{0.0f, 0.0f};
            #pragma unroll
            for (int j = 0; j < 4; ++j) {
                const f2 d = PA[j] - PB[j];
                acc = fma2(d, d, acc);
            }
            mse_local = acc.x + acc.y;
        }

        const int x0s = 4 * seg;
        // pass 1: linear signals (packed across the row pair)
        {
            f2 s1[4], s2[4];
            #pragma unroll
            for (int j = 0; j < 4; ++j) { s1[j] = f2{0,0}; s2[j] = f2{0,0}; }
            #pragma unroll
            for (int k = 0; k < 16; ++k) {
                const float wk = win.g[k];
                const f2 w = f2{wk, wk};
                #pragma unroll
                for (int j = 0; j < 4; ++j) {
                    s1[j] = fma2(w, PA[j + k], s1[j]);
                    s2[j] = fma2(w, PB[j + k], s2[j]);
                }
            }
            #pragma unroll
            for (int j = 0; j < 4; ++j) {
                hb[0][r0][x0s + j] = s1[j].x;
                hb[1][r0][x0s + j] = s2[j].x;
            }
            if (r1 < TIN) {
                #pragma unroll
                for (int j = 0; j < 4; ++j) {
                    hb[0][r1][x0s + j] = s1[j].y;
                    hb[1][r1][x0s + j] = s2[j].y;
                }
            }
        }
        // transform in place: PA := a^2+b^2, PB := a*b
        #pragma unroll
        for (int i = 0; i < 19; ++i) {
            const f2 a = PA[i], b = PB[i];
            PA[i] = fma2(a, a, b * b);
            PB[i] = a * b;
        }
        // pass 2: quadratic signals
        {
            f2 sq[4], sx[4];
            #pragma unroll
            for (int j = 0; j < 4; ++j) { sq[j] = f2{0,0}; sx[j] = f2{0,0}; }
            #pragma unroll
            for (int k = 0; k < 16; ++k) {
                const float wk = win.g[k];
                const f2 w = f2{wk, wk};
                #pragma unroll
                for (int j = 0; j < 4; ++j) {
                    sq[j] = fma2(w, PA[j + k], sq[j]);
                    sx[j] = fma2(w, PB[j + k], sx[j]);
                }
            }
            #pragma unroll
            for (int j = 0; j < 4; ++j) {
                hb[2][r0][x0s + j] = sq[j].x;
                hb[3][r0][x0s + j] = sx[j].x;
            }
            if (r1 < TIN) {
                #pragma unroll
                for (int j = 0; j < 4; ++j) {
                    hb[2][r1][x0s + j] = sq[j].y;
                    hb[3][r1][x0s + j] = sx[j].y;
                }
            }
        }
    }
    __syncthreads();

    // ---------------- Phase C: vertical conv + SSIM map ----------------
    float ssim_local = 0.0f;
    if (tid < 128) {
        const int cp  = tid & 15;       // col pair -> cols 2cp, 2cp+1
        const int rg  = tid >> 4;       // 0..7 -> rows 4rg..4rg+3
        const int yo0 = 4 * rg;
        const int x0  = 2 * cp;
        const int limx = OUTW - ox0;
        const int limy = OUTW - oy0;

        f2 m1[4], m2[4], mq[4], mx[4];
        #pragma unroll
        for (int j = 0; j < 4; ++j) {
            m1[j] = f2{0,0}; m2[j] = f2{0,0}; mq[j] = f2{0,0}; mx[j] = f2{0,0};
        }

        #define VCONV(S, ACC)                                               \
        {                                                                   \
            f2 v[19];                                                       \
            _Pragma("unroll")                                               \
            for (int k = 0; k < 19; ++k)                                    \
                v[k] = *(const f2*)&hb[S][yo0 + k][x0];                     \
            _Pragma("unroll")                                               \
            for (int j = 0; j < 4; ++j) {                                   \
                _Pragma("unroll")                                           \
                for (int k = 0; k < 16; ++k) {                              \
                    const float wk = win.g[k];                              \
                    ACC[j] = fma2(f2{wk, wk}, v[j + k], ACC[j]);            \
                }                                                           \
            }                                                               \
        }
        VCONV(0, m1) VCONV(1, m2) VCONV(2, mq) VCONV(3, mx)
        #undef VCONV

        const f2 C1u = f2{1.0e-4f, 1.0e-4f};   // (0.01*255)^2 / 255^2
        const f2 C2u = f2{9.0e-4f, 9.0e-4f};   // (0.03*255)^2 / 255^2
        const f2 two = f2{2.0f, 2.0f};
        #pragma unroll
        for (int j = 0; j < 4; ++j) {
            const f2 mu1  = m1[j], mu2 = m2[j];
            const f2 mu12 = mu1 * mu2;
            const f2 musq = fma2(mu1, mu1, mu2 * mu2);
            const f2 sgq  = mq[j] - musq;          // sigma1^2 + sigma2^2
            const f2 sg12 = mx[j] - mu12;
            const f2 num  = fma2(two, mu12, C1u) * fma2(two, sg12, C2u);
            const f2 den  = (musq + C1u) * (sgq + C2u);
            const f2 val  = num * f2{__builtin_amdgcn_rcpf(den.x),
                                     __builtin_amdgcn_rcpf(den.y)};
            if (yo0 + j < limy) {
                if (x0 < limx)     ssim_local += val.x;
                if (x0 + 1 < limx) ssim_local += val.y;
            }
        }
    }

    // ---------------- Block reduction + partial write ----------------
    #pragma unroll
    for (int off = 32; off > 0; off >>= 1) {
        mse_local  += __shfl_down(mse_local,  off, 64);
        ssim_local += __shfl_down(ssim_local, off, 64);
    }
    const int wave = tid >> 6;
    if ((tid & 63) == 0) { red[0][wave] = mse_local; red[1][wave] = ssim_local; }
    __syncthreads();
    if (tid == 0) {
        const double m = (double)red[0][0] + (double)red[0][1]
                       + (double)red[0][2] + (double)red[0][3];
        const double s = (double)red[1][0] + (double)red[1][1]
                       + (double)red[1][2] + (double)red[1][3];
        if (TWO_STAGE) {
            const int bid = (int)blockIdx.x
                          + 16 * ((int)blockIdx.y + 16 * (int)blockIdx.z);
            partial[bid] = make_double2(m, s);
        } else {
            atomicAdd(&accum[0], m);
            atomicAdd(&accum[1], s);
        }
    }
}

// Single block, 1024 threads: 24576 partials = 1024 x 24 exactly.
__global__ __launch_bounds__(1024) void reduce_kernel(
    const double2* __restrict__ partial,
    float* __restrict__ out)
{
    __shared__ double sm[16], ss[16];
    const int tid = threadIdx.x;
    double m = 0.0, s = 0.0;
    #pragma unroll
    for (int k = 0; k < 24; ++k) {
        const double2 p = partial[tid + 1024 * k];
        m += p.x; s += p.y;
    }
    #pragma unroll
    for (int off = 32; off > 0; off >>= 1) {
        m += __shfl_down(m, off, 64);
        s += __shfl_down(s, off, 64);
    }
    if ((tid & 63) == 0) { sm[tid >> 6] = m; ss[tid >> 6] = s; }
    __syncthreads();
    if (tid == 0) {
        double M = 0.0, S = 0.0;
        #pragma unroll
        for (int w = 0; w < 16; ++w) { M += sm[w]; S += ss[w]; }
        const double mse  = M / 25165824.0;   // 32*3*512*512
        const double ssim = S / 23712864.0;   // 32*3*497*497
        out[0] = (float)(0.7 * mse + 0.3 * (1.0 - ssim));
    }
}

__global__ void finalize_kernel(const double* __restrict__ accum,
                                float* __restrict__ out)
{
    const double mse  = accum[0] / 25165824.0;
    const double ssim = accum[1] / 23712864.0;
    out[0] = (float)(0.7 * mse + 0.3 * (1.0 - ssim));
}

extern "C" void kernel_launch(void* const* d_in, const int* in_sizes, int n_in,
                              void* d_out, int out_size, void* d_ws, size_t ws_size,
                              hipStream_t stream) {
    const float* img1 = (const float*)d_in[0];
    const float* img2 = (const float*)d_in[1];
    float* out = (float*)d_out;

    GaussWin win;
    {
        double g[16], s = 0.0;
        for (int i = 0; i < 16; ++i) {
            const double c = (double)i - 7.5;
            g[i] = exp(-(c * c) / 4.5);
            s += g[i];
        }
        for (int i = 0; i < 16; ++i) win.g[i] = (float)(g[i] / s);
    }

    dim3 grid(16, 16, 96);   // 16x16 tiles of 497x497, 96 = 32*3 planes
    if (ws_size >= (size_t)NBLK * sizeof(double2)) {
        double2* partial = (double2*)d_ws;
        ssim_mse_kernel<true><<<grid, dim3(256), 0, stream>>>(
            img1, img2, win, partial, nullptr);
        reduce_kernel<<<1, dim3(1024), 0, stream>>>(partial, out);
    } else {
        double* accum = (double*)d_ws;
        hipMemsetAsync(d_ws, 0, 2 * sizeof(double), stream);
        ssim_mse_kernel<false><<<grid, dim3(256), 0, stream>>>(
            img1, img2, win, nullptr, accum);
        finalize_kernel<<<1, 1, 0, stream>>>(accum, out);
    }
}

// Round 5
// 586.959 us; speedup vs baseline: 1.0220x; 1.0220x over previous
//
#include <hip/hip_runtime.h>
#include <math.h>

typedef float f2 __attribute__((ext_vector_type(2)));

namespace {
constexpr int TOUT = 32;            // output tile side
constexpr int HALO = 15;            // 16-tap VALID conv halo
constexpr int TIN  = TOUT + HALO;   // 47 rows of horizontal-conv output
constexpr int HLD  = 36;            // hb row stride (floats), 144 B
constexpr int IMG  = 512;
constexpr int OUTW = IMG - HALO;    // 497
constexpr int NBLK = 16 * 16 * 96;  // 24576 blocks

struct GaussWin { float g[16]; };

__device__ __forceinline__ f2 fma2(f2 a, f2 b, f2 c) {
    return __builtin_elementwise_fma(a, b, c);
}
}

// One block = one 32x32 output tile of one (batch,channel) plane.
// Packed-f32 (v_pk_fma_f32): phase AB packs ROW PAIRS, phase C packs COLUMN
// PAIRS (b64 LDS reads). R4 lesson: with __launch_bounds__(256,4) the
// allocator squeezed VGPRs to 64 (8 waves/EU target) and spilled the f2
// arrays -> 432 MB scratch writes, 287->482 us regression. Fix: pin
// amdgpu_waves_per_eu(4,4) -> VGPR budget exactly 128, no spill.
// Phase AB: 192 threads = 24 row-pairs x 8 col-segments of 4 outputs. Load
//   19 floats x 2 rows x 2 images into f2 regs, fuse MSE, 16-tap horizontal
//   conv for 4 signals (a, b, a^2+b^2, a*b), scalar-store into hb[4][47][36].
// Phase C: 128 threads = 16 col-pairs x 8 row-groups of 4. 19 b64 reads per
//   signal serve 4x2 outputs; packed vertical conv; SSIM map with v_rcp.
// Tail: per-block double2 partial (R2: same-address f64 atomics serialize at
//   ~13 ns each = 2.2x whole-kernel cost); reduce_kernel sums.
template <bool TWO_STAGE>
__global__ __launch_bounds__(256)
__attribute__((amdgpu_waves_per_eu(4, 4)))
void ssim_mse_kernel(
    const float* __restrict__ img1,
    const float* __restrict__ img2,
    GaussWin win,
    double2* __restrict__ partial,
    double*  __restrict__ accum)
{
    __shared__ float hb[4][TIN][HLD];   // 27,072 B -> 6 blocks/CU by LDS
    __shared__ float red[2][4];

    const int tid = threadIdx.x;
    const int ox0 = blockIdx.x * TOUT;
    const int oy0 = blockIdx.y * TOUT;
    const size_t plane_off = (size_t)blockIdx.z * (IMG * IMG);
    const float* __restrict__ p1 = img1 + plane_off;
    const float* __restrict__ p2 = img2 + plane_off;

    float mse_local = 0.0f;

    // ---------------- Phase AB: load + MSE + horizontal conv ----------------
    if (tid < 192) {
        const int pr  = tid >> 3;       // row pair 0..23 -> rows 2pr, 2pr+1
        const int seg = tid & 7;        // col segment: 4 outputs each
        const int r0  = 2 * pr;
        const int r1  = r0 + 1;
        const int gy0 = oy0 + r0;
        const int gy1 = oy0 + r1;
        const int c0  = ox0 + 4 * seg;

        f2 PA[19], PB[19];              // (row0, row1) packed
        const bool fast = (gy1 < IMG) & (c0 + 19 <= IMG);
        if (fast) {
            const float* __restrict__ pa0 = p1 + (size_t)gy0 * IMG + c0;
            const float* __restrict__ pa1 = pa0 + IMG;
            const float* __restrict__ pb0 = p2 + (size_t)gy0 * IMG + c0;
            const float* __restrict__ pb1 = pb0 + IMG;
            #pragma unroll
            for (int q = 0; q < 4; ++q) {
                const float4 a0 = *(const float4*)(pa0 + 4 * q);
                const float4 a1 = *(const float4*)(pa1 + 4 * q);
                const float4 b0 = *(const float4*)(pb0 + 4 * q);
                const float4 b1 = *(const float4*)(pb1 + 4 * q);
                PA[4*q+0] = f2{a0.x, a1.x}; PA[4*q+1] = f2{a0.y, a1.y};
                PA[4*q+2] = f2{a0.z, a1.z}; PA[4*q+3] = f2{a0.w, a1.w};
                PB[4*q+0] = f2{b0.x, b1.x}; PB[4*q+1] = f2{b0.y, b1.y};
                PB[4*q+2] = f2{b0.z, b1.z}; PB[4*q+3] = f2{b0.w, b1.w};
            }
            const float2 ta0 = *(const float2*)(pa0 + 16);
            const float2 ta1 = *(const float2*)(pa1 + 16);
            const float2 tb0 = *(const float2*)(pb0 + 16);
            const float2 tb1 = *(const float2*)(pb1 + 16);
            PA[16] = f2{ta0.x, ta1.x}; PA[17] = f2{ta0.y, ta1.y};
            PB[16] = f2{tb0.x, tb1.x}; PB[17] = f2{tb0.y, tb1.y};
            PA[18] = f2{pa0[18], pa1[18]};
            PB[18] = f2{pb0[18], pb1[18]};
        } else {
            const int g0 = gy0 < IMG ? gy0 : (IMG - 1);
            const int g1 = gy1 < IMG ? gy1 : (IMG - 1);
            const float* __restrict__ pa0 = p1 + (size_t)g0 * IMG;
            const float* __restrict__ pa1 = p1 + (size_t)g1 * IMG;
            const float* __restrict__ pb0 = p2 + (size_t)g0 * IMG;
            const float* __restrict__ pb1 = p2 + (size_t)g1 * IMG;
            #pragma unroll
            for (int k = 0; k < 19; ++k) {
                const int gx = (c0 + k) < IMG ? (c0 + k) : (IMG - 1);
                PA[k] = f2{pa0[gx], pa1[gx]};
                PB[k] = f2{pb0[gx], pb1[gx]};
            }
        }

        // MSE over owned pixels: row pairs 0..15 (= rows 0..31), 4 owned cols
        if (pr < 16) {
            f2 acc = f2{0.0f, 0.0f};
            #pragma unroll
            for (int j = 0; j < 4; ++j) {
                const f2 d = PA[j] - PB[j];
                acc = fma2(d, d, acc);
            }
            mse_local = acc.x + acc.y;
        }

        const int x0s = 4 * seg;
        // pass 1: linear signals (packed across the row pair)
        {
            f2 s1[4], s2[4];
            #pragma unroll
            for (int j = 0; j < 4; ++j) { s1[j] = f2{0,0}; s2[j] = f2{0,0}; }
            #pragma unroll
            for (int k = 0; k < 16; ++k) {
                const float wk = win.g[k];
                const f2 w = f2{wk, wk};
                #pragma unroll
                for (int j = 0; j < 4; ++j) {
                    s1[j] = fma2(w, PA[j + k], s1[j]);
                    s2[j] = fma2(w, PB[j + k], s2[j]);
                }
            }
            #pragma unroll
            for (int j = 0; j < 4; ++j) {
                hb[0][r0][x0s + j] = s1[j].x;
                hb[1][r0][x0s + j] = s2[j].x;
            }
            if (r1 < TIN) {
                #pragma unroll
                for (int j = 0; j < 4; ++j) {
                    hb[0][r1][x0s + j] = s1[j].y;
                    hb[1][r1][x0s + j] = s2[j].y;
                }
            }
        }
        // transform in place: PA := a^2+b^2, PB := a*b
        #pragma unroll
        for (int i = 0; i < 19; ++i) {
            const f2 a = PA[i], b = PB[i];
            PA[i] = fma2(a, a, b * b);
            PB[i] = a * b;
        }
        // pass 2: quadratic signals
        {
            f2 sq[4], sx[4];
            #pragma unroll
            for (int j = 0; j < 4; ++j) { sq[j] = f2{0,0}; sx[j] = f2{0,0}; }
            #pragma unroll
            for (int k = 0; k < 16; ++k) {
                const float wk = win.g[k];
                const f2 w = f2{wk, wk};
                #pragma unroll
                for (int j = 0; j < 4; ++j) {
                    sq[j] = fma2(w, PA[j + k], sq[j]);
                    sx[j] = fma2(w, PB[j + k], sx[j]);
                }
            }
            #pragma unroll
            for (int j = 0; j < 4; ++j) {
                hb[2][r0][x0s + j] = sq[j].x;
                hb[3][r0][x0s + j] = sx[j].x;
            }
            if (r1 < TIN) {
                #pragma unroll
                for (int j = 0; j < 4; ++j) {
                    hb[2][r1][x0s + j] = sq[j].y;
                    hb[3][r1][x0s + j] = sx[j].y;
                }
            }
        }
    }
    __syncthreads();

    // ---------------- Phase C: vertical conv + SSIM map ----------------
    float ssim_local = 0.0f;
    if (tid < 128) {
        const int cp  = tid & 15;       // col pair -> cols 2cp, 2cp+1
        const int rg  = tid >> 4;       // 0..7 -> rows 4rg..4rg+3
        const int yo0 = 4 * rg;
        const int x0  = 2 * cp;
        const int limx = OUTW - ox0;
        const int limy = OUTW - oy0;

        f2 m1[4], m2[4], mq[4], mx[4];
        #pragma unroll
        for (int j = 0; j < 4; ++j) {
            m1[j] = f2{0,0}; m2[j] = f2{0,0}; mq[j] = f2{0,0}; mx[j] = f2{0,0};
        }

        #define VCONV(S, ACC)                                               \
        {                                                                   \
            f2 v[19];                                                       \
            _Pragma("unroll")                                               \
            for (int k = 0; k < 19; ++k)                                    \
                v[k] = *(const f2*)&hb[S][yo0 + k][x0];                     \
            _Pragma("unroll")                                               \
            for (int j = 0; j < 4; ++j) {                                   \
                _Pragma("unroll")                                           \
                for (int k = 0; k < 16; ++k) {                              \
                    const float wk = win.g[k];                              \
                    ACC[j] = fma2(f2{wk, wk}, v[j + k], ACC[j]);            \
                }                                                           \
            }                                                               \
        }
        VCONV(0, m1) VCONV(1, m2) VCONV(2, mq) VCONV(3, mx)
        #undef VCONV

        const f2 C1u = f2{1.0e-4f, 1.0e-4f};   // (0.01*255)^2 / 255^2
        const f2 C2u = f2{9.0e-4f, 9.0e-4f};   // (0.03*255)^2 / 255^2
        const f2 two = f2{2.0f, 2.0f};
        #pragma unroll
        for (int j = 0; j < 4; ++j) {
            const f2 mu1  = m1[j], mu2 = m2[j];
            const f2 mu12 = mu1 * mu2;
            const f2 musq = fma2(mu1, mu1, mu2 * mu2);
            const f2 sgq  = mq[j] - musq;          // sigma1^2 + sigma2^2
            const f2 sg12 = mx[j] - mu12;
            const f2 num  = fma2(two, mu12, C1u) * fma2(two, sg12, C2u);
            const f2 den  = (musq + C1u) * (sgq + C2u);
            const f2 val  = num * f2{__builtin_amdgcn_rcpf(den.x),
                                     __builtin_amdgcn_rcpf(den.y)};
            if (yo0 + j < limy) {
                if (x0 < limx)     ssim_local += val.x;
                if (x0 + 1 < limx) ssim_local += val.y;
            }
        }
    }

    // ---------------- Block reduction + partial write ----------------
    #pragma unroll
    for (int off = 32; off > 0; off >>= 1) {
        mse_local  += __shfl_down(mse_local,  off, 64);
        ssim_local += __shfl_down(ssim_local, off, 64);
    }
    const int wave = tid >> 6;
    if ((tid & 63) == 0) { red[0][wave] = mse_local; red[1][wave] = ssim_local; }
    __syncthreads();
    if (tid == 0) {
        const double m = (double)red[0][0] + (double)red[0][1]
                       + (double)red[0][2] + (double)red[0][3];
        const double s = (double)red[1][0] + (double)red[1][1]
                       + (double)red[1][2] + (double)red[1][3];
        if (TWO_STAGE) {
            const int bid = (int)blockIdx.x
                          + 16 * ((int)blockIdx.y + 16 * (int)blockIdx.z);
            partial[bid] = make_double2(m, s);
        } else {
            atomicAdd(&accum[0], m);
            atomicAdd(&accum[1], s);
        }
    }
}

// Single block, 1024 threads: 24576 partials = 1024 x 24 exactly.
__global__ __launch_bounds__(1024) void reduce_kernel(
    const double2* __restrict__ partial,
    float* __restrict__ out)
{
    __shared__ double sm[16], ss[16];
    const int tid = threadIdx.x;
    double m = 0.0, s = 0.0;
    #pragma unroll
    for (int k = 0; k < 24; ++k) {
        const double2 p = partial[tid + 1024 * k];
        m += p.x; s += p.y;
    }
    #pragma unroll
    for (int off = 32; off > 0; off >>= 1) {
        m += __shfl_down(m, off, 64);
        s += __shfl_down(s, off, 64);
    }
    if ((tid & 63) == 0) { sm[tid >> 6] = m; ss[tid >> 6] = s; }
    __syncthreads();
    if (tid == 0) {
        double M = 0.0, S = 0.0;
        #pragma unroll
        for (int w = 0; w < 16; ++w) { M += sm[w]; S += ss[w]; }
        const double mse  = M / 25165824.0;   // 32*3*512*512
        const double ssim = S / 23712864.0;   // 32*3*497*497
        out[0] = (float)(0.7 * mse + 0.3 * (1.0 - ssim));
    }
}

__global__ void finalize_kernel(const double* __restrict__ accum,
                                float* __restrict__ out)
{
    const double mse  = accum[0] / 25165824.0;
    const double ssim = accum[1] / 23712864.0;
    out[0] = (float)(0.7 * mse + 0.3 * (1.0 - ssim));
}

extern "C" void kernel_launch(void* const* d_in, const int* in_sizes, int n_in,
                              void* d_out, int out_size, void* d_ws, size_t ws_size,
                              hipStream_t stream) {
    const float* img1 = (const float*)d_in[0];
    const float* img2 = (const float*)d_in[1];
    float* out = (float*)d_out;

    GaussWin win;
    {
        double g[16], s = 0.0;
        for (int i = 0; i < 16; ++i) {
            const double c = (double)i - 7.5;
            g[i] = exp(-(c * c) / 4.5);
            s += g[i];
        }
        for (int i = 0; i < 16; ++i) win.g[i] = (float)(g[i] / s);
    }

    dim3 grid(16, 16, 96);   // 16x16 tiles of 497x497, 96 = 32*3 planes
    if (ws_size >= (size_t)NBLK * sizeof(double2)) {
        double2* partial = (double2*)d_ws;
        ssim_mse_kernel<true><<<grid, dim3(256), 0, stream>>>(
            img1, img2, win, partial, nullptr);
        reduce_kernel<<<1, dim3(1024), 0, stream>>>(partial, out);
    } else {
        double* accum = (double*)d_ws;
        hipMemsetAsync(d_ws, 0, 2 * sizeof(double), stream);
        ssim_mse_kernel<false><<<grid, dim3(256), 0, stream>>>(
            img1, img2, win, nullptr, accum);
        finalize_kernel<<<1, 1, 0, stream>>>(accum, out);
    }
}

// Round 6
// 351.159 us; speedup vs baseline: 1.7082x; 1.6715x over previous
//
#include <hip/hip_runtime.h>
#include <math.h>

typedef float f2 __attribute__((ext_vector_type(2)));

namespace {
constexpr int TOUT = 32;            // output tile side
constexpr int HALO = 15;            // 16-tap VALID conv halo
constexpr int TIN  = TOUT + HALO;   // 47 rows of horizontal-conv output
constexpr int HLD  = 37;            // hb row stride in f2 units (74 floats, padded)
constexpr int IMG  = 512;
constexpr int OUTW = IMG - HALO;    // 497
constexpr int NBLK = 16 * 16 * 96;  // 24576 blocks

struct GaussWin { float g[16]; };

__device__ __forceinline__ f2 fma2(f2 a, f2 b, f2 c) {
    return __builtin_elementwise_fma(a, b, c);
}
}

// One block = one 32x32 output tile of one (batch,channel) plane.
//
// R4/R5 lesson: the allocator pins this kernel at a 64-VGPR budget and
// SPILLS to stay there (418 MB scratch; amdgpu_waves_per_eu ignored).
// So: pack across SIGNALS, not rows, and stream inputs so peak live < 64.
//   f2 lane pair = {a, b} for linear signals, {a^2+b^2, a*b} for quadratic.
//
// Phase AB: 188 threads = 47 rows x 4 col-segments of 8 outputs. Single
//   fused pass over 23 inputs in chunks of 4 (float4 loads, consumed
//   immediately): each input updates the <=8 affected outputs of both
//   packed streams (v_pk_fma_f32). Peak live ~55 VGPR. MSE fused on the
//   owned 32x8 pixels. b64 stores to interleaved hb[2][47][37] f2.
// Phase C: 256 threads = 32 cols x 8 row-groups of 4. Vertical 16-tap conv
//   streamed in 4-row chunks (b64 reads, consumed immediately); packed
//   conv for both streams; SSIM map with v_rcp. Peak live ~50 VGPR.
// Tail: per-block double2 partial (R2: same-address f64 atomics serialize
//   ~13ns each = 2.2x whole-kernel cost); reduce_kernel sums.
template <bool TWO_STAGE>
__global__ __launch_bounds__(256)
void ssim_mse_kernel(
    const float* __restrict__ img1,
    const float* __restrict__ img2,
    GaussWin win,
    double2* __restrict__ partial,
    double*  __restrict__ accum)
{
    __shared__ f2 hb[2][TIN][HLD];      // 2*47*37*8 = 27,824 B
    __shared__ float red[2][4];

    const int tid = threadIdx.x;
    const int ox0 = blockIdx.x * TOUT;
    const int oy0 = blockIdx.y * TOUT;
    const size_t plane_off = (size_t)blockIdx.z * (IMG * IMG);
    const float* __restrict__ p1 = img1 + plane_off;
    const float* __restrict__ p2 = img2 + plane_off;

    float mse_local = 0.0f;

    // ---------------- Phase AB: load + MSE + horizontal conv ----------------
    if (tid < TIN * 4) {
        const int r   = tid >> 2;       // row 0..46
        const int seg = tid & 3;        // col segment: 8 outputs each
        const int gy  = oy0 + r;
        const int c0  = ox0 + 8 * seg;
        const bool ownrow = (r < TOUT);

        const int gyc = gy < IMG ? gy : (IMG - 1);
        const float* __restrict__ pa = p1 + (size_t)gyc * IMG;
        const float* __restrict__ pb = p2 + (size_t)gyc * IMG;
        const bool fast = (c0 + 23 <= IMG);

        f2 accl[8], accq[8];
        #pragma unroll
        for (int j = 0; j < 8; ++j) { accl[j] = f2{0,0}; accq[j] = f2{0,0}; }

        #pragma unroll
        for (int ch = 0; ch < 6; ++ch) {
            const int ib = 4 * ch;
            const int n  = (ch == 5) ? 3 : 4;

            f2 in[4];
            if (fast) {
                if (n == 4) {
                    const float4 la = *(const float4*)(pa + c0 + ib);
                    const float4 lb = *(const float4*)(pb + c0 + ib);
                    in[0] = f2{la.x, lb.x}; in[1] = f2{la.y, lb.y};
                    in[2] = f2{la.z, lb.z}; in[3] = f2{la.w, lb.w};
                } else {
                    const float2 la = *(const float2*)(pa + c0 + 20);
                    const float2 lb = *(const float2*)(pb + c0 + 20);
                    in[0] = f2{la.x, lb.x}; in[1] = f2{la.y, lb.y};
                    in[2] = f2{pa[c0 + 22], pb[c0 + 22]};
                }
            } else {
                #pragma unroll
                for (int t = 0; t < 4; ++t) {
                    if (t < n) {
                        const int gx = (c0 + ib + t) < IMG ? (c0 + ib + t) : (IMG - 1);
                        in[t] = f2{pa[gx], pb[gx]};
                    }
                }
            }

            #pragma unroll
            for (int t = 0; t < 4; ++t) {
                if (t >= n) continue;
                const int i = ib + t;
                const f2 v  = in[t];
                const f2 qx = f2{fmaf(v.x, v.x, v.y * v.y), v.x * v.y};
                if (i < 8 && ownrow) {       // owned pixel -> MSE
                    const float d = v.x - v.y;
                    mse_local = fmaf(d, d, mse_local);
                }
                const int jlo = (i > 15) ? (i - 15) : 0;
                const int jhi = (i < 7) ? i : 7;
                #pragma unroll
                for (int j = 0; j < 8; ++j) {
                    if (j < jlo || j > jhi) continue;
                    const float w = win.g[i - j];
                    const f2 w2 = f2{w, w};
                    accl[j] = fma2(w2, v,  accl[j]);
                    accq[j] = fma2(w2, qx, accq[j]);
                }
            }
        }

        #pragma unroll
        for (int j = 0; j < 8; ++j) {
            const int c = 8 * seg + j;
            hb[0][r][c] = accl[j];
            hb[1][r][c] = accq[j];
        }
    }
    __syncthreads();

    // ---------------- Phase C: vertical conv + SSIM map ----------------
    float ssim_local = 0.0f;
    {
        const int c   = tid & 31;       // column 0..31
        const int rg  = tid >> 5;       // 0..7 -> rows 4rg..4rg+3
        const int yo0 = 4 * rg;
        const int limx = OUTW - ox0;
        const int limy = OUTW - oy0;

        f2 aL[4], aQ[4];
        #pragma unroll
        for (int j = 0; j < 4; ++j) { aL[j] = f2{0,0}; aQ[j] = f2{0,0}; }

        #pragma unroll
        for (int kb = 0; kb < 5; ++kb) {
            const int nk = (kb == 4) ? 3 : 4;
            f2 vL[4], vQ[4];
            #pragma unroll
            for (int t = 0; t < 4; ++t) {
                if (t < nk) {
                    vL[t] = hb[0][yo0 + 4 * kb + t][c];
                    vQ[t] = hb[1][yo0 + 4 * kb + t][c];
                }
            }
            #pragma unroll
            for (int t = 0; t < 4; ++t) {
                if (t >= nk) continue;
                const int k = 4 * kb + t;
                const int jlo = (k > 15) ? (k - 15) : 0;
                const int jhi = (k < 3) ? k : 3;
                #pragma unroll
                for (int j = 0; j < 4; ++j) {
                    if (j < jlo || j > jhi) continue;
                    const float w = win.g[k - j];
                    const f2 w2 = f2{w, w};
                    aL[j] = fma2(w2, vL[t], aL[j]);
                    aQ[j] = fma2(w2, vQ[t], aQ[j]);
                }
            }
        }

        const float C1u = 1.0e-4f;   // (0.01*255)^2 / 255^2
        const float C2u = 9.0e-4f;   // (0.03*255)^2 / 255^2
        #pragma unroll
        for (int j = 0; j < 4; ++j) {
            const float mu1  = aL[j].x, mu2 = aL[j].y;
            const float mu12 = mu1 * mu2;
            const float musq = fmaf(mu1, mu1, mu2 * mu2);
            const float sgq  = aQ[j].x - musq;     // sigma1^2 + sigma2^2
            const float sg12 = aQ[j].y - mu12;
            const float num  = fmaf(2.0f, mu12, C1u) * fmaf(2.0f, sg12, C2u);
            const float den  = (musq + C1u) * (sgq + C2u);
            const float val  = num * __builtin_amdgcn_rcpf(den);
            if (c < limx && (yo0 + j) < limy) ssim_local += val;
        }
    }

    // ---------------- Block reduction + partial write ----------------
    #pragma unroll
    for (int off = 32; off > 0; off >>= 1) {
        mse_local  += __shfl_down(mse_local,  off, 64);
        ssim_local += __shfl_down(ssim_local, off, 64);
    }
    const int wave = tid >> 6;
    if ((tid & 63) == 0) { red[0][wave] = mse_local; red[1][wave] = ssim_local; }
    __syncthreads();
    if (tid == 0) {
        const double m = (double)red[0][0] + (double)red[0][1]
                       + (double)red[0][2] + (double)red[0][3];
        const double s = (double)red[1][0] + (double)red[1][1]
                       + (double)red[1][2] + (double)red[1][3];
        if (TWO_STAGE) {
            const int bid = (int)blockIdx.x
                          + 16 * ((int)blockIdx.y + 16 * (int)blockIdx.z);
            partial[bid] = make_double2(m, s);
        } else {
            atomicAdd(&accum[0], m);
            atomicAdd(&accum[1], s);
        }
    }
}

// Single block, 1024 threads: 24576 partials = 1024 x 24 exactly.
__global__ __launch_bounds__(1024) void reduce_kernel(
    const double2* __restrict__ partial,
    float* __restrict__ out)
{
    __shared__ double sm[16], ss[16];
    const int tid = threadIdx.x;
    double m = 0.0, s = 0.0;
    #pragma unroll
    for (int k = 0; k < 24; ++k) {
        const double2 p = partial[tid + 1024 * k];
        m += p.x; s += p.y;
    }
    #pragma unroll
    for (int off = 32; off > 0; off >>= 1) {
        m += __shfl_down(m, off, 64);
        s += __shfl_down(s, off, 64);
    }
    if ((tid & 63) == 0) { sm[tid >> 6] = m; ss[tid >> 6] = s; }
    __syncthreads();
    if (tid == 0) {
        double M = 0.0, S = 0.0;
        #pragma unroll
        for (int w = 0; w < 16; ++w) { M += sm[w]; S += ss[w]; }
        const double mse  = M / 25165824.0;   // 32*3*512*512
        const double ssim = S / 23712864.0;   // 32*3*497*497
        out[0] = (float)(0.7 * mse + 0.3 * (1.0 - ssim));
    }
}

__global__ void finalize_kernel(const double* __restrict__ accum,
                                float* __restrict__ out)
{
    const double mse  = accum[0] / 25165824.0;
    const double ssim = accum[1] / 23712864.0;
    out[0] = (float)(0.7 * mse + 0.3 * (1.0 - ssim));
}

extern "C" void kernel_launch(void* const* d_in, const int* in_sizes, int n_in,
                              void* d_out, int out_size, void* d_ws, size_t ws_size,
                              hipStream_t stream) {
    const float* img1 = (const float*)d_in[0];
    const float* img2 = (const float*)d_in[1];
    float* out = (float*)d_out;

    GaussWin win;
    {
        double g[16], s = 0.0;
        for (int i = 0; i < 16; ++i) {
            const double c = (double)i - 7.5;
            g[i] = exp(-(c * c) / 4.5);
            s += g[i];
        }
        for (int i = 0; i < 16; ++i) win.g[i] = (float)(g[i] / s);
    }

    dim3 grid(16, 16, 96);   // 16x16 tiles of 497x497, 96 = 32*3 planes
    if (ws_size >= (size_t)NBLK * sizeof(double2)) {
        double2* partial = (double2*)d_ws;
        ssim_mse_kernel<true><<<grid, dim3(256), 0, stream>>>(
            img1, img2, win, partial, nullptr);
        reduce_kernel<<<1, dim3(1024), 0, stream>>>(partial, out);
    } else {
        double* accum = (double*)d_ws;
        hipMemsetAsync(d_ws, 0, 2 * sizeof(double), stream);
        ssim_mse_kernel<false><<<grid, dim3(256), 0, stream>>>(
            img1, img2, win, nullptr, accum);
        finalize_kernel<<<1, 1, 0, stream>>>(accum, out);
    }
}